// Round 12
// baseline (494.403 us; speedup 1.0000x reference)
//
#include <hip/hip_runtime.h>
#include <hip/hip_bf16.h>
#include <cstdint>
#include <cstddef>

#define NN 50000
#define EE 400000

typedef __attribute__((ext_vector_type(8))) __bf16 bf16x8;
typedef __attribute__((ext_vector_type(4))) float f32x4;

// ---------------- helpers ----------------
static __device__ __forceinline__ float dec_key(unsigned k) {
  return (k & 0x80000000u) ? __uint_as_float(k & 0x7fffffffu) : __uint_as_float(~k);
}
static __device__ __forceinline__ unsigned enc_key(float f) {
  unsigned b = __float_as_uint(f);
  return (f >= 0.f) ? (b | 0x80000000u) : ~b;
}

// ---------------- CSR build ----------------
__global__ void count_kernel(const int* __restrict__ dst, int* __restrict__ cnt, int e) {
  int i = blockIdx.x * blockDim.x + threadIdx.x;
  if (i < e) atomicAdd(&cnt[dst[i]], 1);
}

__global__ void dis_kernel(const int* __restrict__ cnt, float* __restrict__ dis, int n) {
  int i = blockIdx.x * blockDim.x + threadIdx.x;
  if (i < n) dis[i] = rsqrtf((float)cnt[i] + 1.0f);
}

// hierarchical scan: 1024 elems per block (4/thread), shuffle wave-scan
#define SCAN_CHUNK 1024
__global__ __launch_bounds__(256) void scan1_kernel(const int* __restrict__ cnt,
                                                    int* __restrict__ rowptr,
                                                    int* __restrict__ bsum, int n) {
  int b = blockIdx.x;
  int base = b * SCAN_CHUNK;
  int t = threadIdx.x;
  int v[4];
  int s = 0;
#pragma unroll
  for (int i = 0; i < 4; ++i) {
    int idx = base + t * 4 + i;
    v[i] = (idx < n) ? cnt[idx] : 0;
    s += v[i];
  }
  int lane = t & 63, w = t >> 6;
  int inc = s;
#pragma unroll
  for (int off = 1; off < 64; off <<= 1) {
    int o = __shfl_up(inc, off, 64);
    if (lane >= off) inc += o;
  }
  __shared__ int wsum[4];
  if (lane == 63) wsum[w] = inc;
  __syncthreads();
  int woff = 0;
  for (int i = 0; i < w; ++i) woff += wsum[i];
  int run = woff + inc - s;
#pragma unroll
  for (int i = 0; i < 4; ++i) {
    int idx = base + t * 4 + i;
    if (idx < n) rowptr[idx] = run;
    run += v[i];
  }
  if (t == 255) bsum[b] = woff + inc;
}

__global__ void scan2_kernel(int* __restrict__ bsum, int nb) {
  int t = threadIdx.x;
  int v = (t < nb) ? bsum[t] : 0;
  int s = v;
#pragma unroll
  for (int off = 1; off < 64; off <<= 1) {
    int o = __shfl_up(s, off, 64);
    if (t >= off) s += o;
  }
  if (t < nb) bsum[t] = s - v;
}

__global__ __launch_bounds__(256) void scan3_kernel(int* __restrict__ rowptr,
                                                    const int* __restrict__ bsum, int n, int total) {
  int i = blockIdx.x * blockDim.x + threadIdx.x;
  if (i < n) rowptr[i] += bsum[i >> 10];
  if (i == 0) rowptr[n] = total;
}

__global__ void fill_kernel(const int* __restrict__ src, const int* __restrict__ dst,
                            const int* __restrict__ rowptr, int* __restrict__ cursor,
                            int* __restrict__ col, int e) {
  int i = blockIdx.x * blockDim.x + threadIdx.x;
  if (i < e) {
    int d = dst[i];
    int p = atomicAdd(&cursor[d], 1);
    col[rowptr[d] + p] = src[i];
  }
}

// ---------------- weight cvt+transpose: Wt[n][k] = bf16(W[k][n]) ----------------
__global__ __launch_bounds__(256) void wcvt_kernel(const float* __restrict__ W,
                                                   __bf16* __restrict__ Wt, int K, int Nout) {
  int idx = blockIdx.x * blockDim.x + threadIdx.x;
  if (idx < K * Nout) {
    int n = idx / K, k = idx - n * K;
    Wt[idx] = (__bf16)W[(size_t)k * Nout + n];
  }
}

// ---------------- f32 GEMM (small K=64 stages): C = A@W, fused epilogue ----------------
#define BM 64
#define BN 64
#define BK 16

__global__ __launch_bounds__(256) void gemm_f32(
    const float* __restrict__ A, const float* __restrict__ W, float* __restrict__ C,
    int M, int K, int Nout, const float* __restrict__ colAdd, int accumulate, int doTanh) {
  __shared__ float As[BK][BM + 4];
  __shared__ float Ws[BK][BN];
  int tid = threadIdx.x;
  int row0 = blockIdx.x * BM;
  int col0 = blockIdx.y * BN;
  int tx = tid & 15;
  int ty = tid >> 4;
  float acc[4][4] = {};
  for (int k0 = 0; k0 < K; k0 += BK) {
#pragma unroll
    for (int i = 0; i < 4; ++i) {
      int idx = tid + i * 256;
      int r = idx >> 4, c = idx & 15;
      int gr = row0 + r;
      float v = (gr < M) ? A[(size_t)gr * K + k0 + c] : 0.f;
      As[c][r] = v;
    }
#pragma unroll
    for (int i = 0; i < 4; ++i) {
      int idx = tid + i * 256;
      int r = idx >> 6, c = idx & 63;
      Ws[r][c] = W[(size_t)(k0 + r) * Nout + col0 + c];
    }
    __syncthreads();
#pragma unroll
    for (int kk = 0; kk < BK; ++kk) {
      float4 av = *(const float4*)&As[kk][ty * 4];
      float4 wv = *(const float4*)&Ws[kk][tx * 4];
      float a[4] = {av.x, av.y, av.z, av.w};
      float w[4] = {wv.x, wv.y, wv.z, wv.w};
#pragma unroll
      for (int i = 0; i < 4; ++i)
#pragma unroll
        for (int j = 0; j < 4; ++j) acc[i][j] = fmaf(a[i], w[j], acc[i][j]);
    }
    __syncthreads();
  }
#pragma unroll
  for (int i = 0; i < 4; ++i) {
    int gr = row0 + ty * 4 + i;
    if (gr >= M) continue;
#pragma unroll
    for (int j = 0; j < 4; ++j) {
      int gc = col0 + tx * 4 + j;
      size_t idx = (size_t)gr * Nout + gc;
      float v = acc[i][j];
      if (colAdd) v += colAdd[gc];
      if (accumulate) v += C[idx];
      if (doTanh) v = tanhf(v);
      C[idx] = v;
    }
  }
}

// ---------------- bf16 MFMA GEMM, NO LDS: A[M,K](bf16) @ Wt[Nout,K](bf16 pre-transposed) ----------------
// Fragment loads go global -> registers directly: lane (lr,lh) of a wave reads
// row (base+lr), bytes [lh*16 .. lh*16+16) of a 64B k-slice -> a wave covers
// 16 rows x 64 contiguous bytes = perfectly coalesced cachelines. No LDS, no
// barriers, no staging; K-loop fully unrolled; latency hidden by TLP.
// OOB rows clamp to M-1 (duplicate values; stores guarded, colmax unaffected).
#define TM 128
#define TN 64

__global__ __launch_bounds__(256) void gemm_mfma(
    const __bf16* __restrict__ A, const __bf16* __restrict__ Wt,
    float* __restrict__ Cf, __bf16* __restrict__ Ch,
    int M, int K, int Nout, const float* __restrict__ colAdd, int doTanh,
    unsigned* __restrict__ colmaxOut) {
  int tid = threadIdx.x;
  int row0 = blockIdx.x * TM;
  int col0 = blockIdx.y * TN;
  int w = tid >> 6, l = tid & 63;
  int lr = l & 15, lh = l >> 4;
  int wmB = (w >> 1) * 64;  // wave row base within tile
  int wnB = (w & 1) * 32;   // wave col base within tile
  // per-lane fragment base pointers (k-offset lh*8 elements)
  const __bf16* arow[4];
#pragma unroll
  for (int mi = 0; mi < 4; ++mi) {
    int r = row0 + wmB + mi * 16 + lr;
    if (r >= M) r = M - 1;  // clamp: duplicate row, harmless
    arow[mi] = A + (size_t)r * K + lh * 8;
  }
  const __bf16* wrow[2];
#pragma unroll
  for (int ni = 0; ni < 2; ++ni) {
    int c = col0 + wnB + ni * 16 + lr;
    wrow[ni] = Wt + (size_t)c * K + lh * 8;
  }
  f32x4 acc[4][2] = {};
#pragma unroll
  for (int ks = 0; ks < 8; ++ks) {  // K/32 steps, K <= 256
    if (ks * 32 >= K) break;
    bf16x8 af[4], bfr[2];
#pragma unroll
    for (int mi = 0; mi < 4; ++mi) af[mi] = *(const bf16x8*)(arow[mi] + ks * 32);
#pragma unroll
    for (int ni = 0; ni < 2; ++ni) bfr[ni] = *(const bf16x8*)(wrow[ni] + ks * 32);
#pragma unroll
    for (int mi = 0; mi < 4; ++mi)
#pragma unroll
      for (int ni = 0; ni < 2; ++ni)
        acc[mi][ni] =
            __builtin_amdgcn_mfma_f32_16x16x32_bf16(af[mi], bfr[ni], acc[mi][ni], 0, 0, 0);
  }
  // epilogue: C/D layout col = lane&15, row = (lane>>4)*4 + reg
  float cmax[2] = {-2.0f, -2.0f};  // tanh outputs in (-1,1); enc_key monotone so -2 sentinel safe
#pragma unroll
  for (int mi = 0; mi < 4; ++mi) {
#pragma unroll
    for (int ni = 0; ni < 2; ++ni) {
#pragma unroll
      for (int r = 0; r < 4; ++r) {
        int gr = row0 + wmB + mi * 16 + lh * 4 + r;
        if (gr >= M) continue;
        int gc = col0 + wnB + ni * 16 + lr;
        size_t idx = (size_t)gr * Nout + gc;
        float v = acc[mi][ni][r];
        if (colAdd) v += colAdd[gc];
        if (doTanh) v = tanhf(v);
        if (colmaxOut) cmax[ni] = fmaxf(cmax[ni], v);
        if (Cf) Cf[idx] = v;
        if (Ch) Ch[idx] = (__bf16)v;
      }
    }
  }
  if (colmaxOut) {
    // lanes {lr, lr+16, lr+32, lr+48} share a column; combine then 1 atomic per col per wave
#pragma unroll
    for (int ni = 0; ni < 2; ++ni) {
      float m = cmax[ni];
      m = fmaxf(m, __shfl_xor(m, 16));
      m = fmaxf(m, __shfl_xor(m, 32));
      if (lh == 0) {
        int gc = col0 + wnB + ni * 16 + lr;
        atomicMax(&colmaxOut[gc], enc_key(m));
      }
    }
  }
}

// ---------------- aggregation: out[d] = sum_{s in N(d)} H[s]*dis[s]*dis[d] + H[d]*dis[d]^2 ----------------
// OT = float or __bf16 output (bf16 out adds NO rounding vs the bf16 MFMA that consumes it)
template <int F, bool EPI, typename OT>
__global__ __launch_bounds__(256) void agg_kernel(
    const float* __restrict__ H, const int* __restrict__ rowptr, const int* __restrict__ col,
    const float* __restrict__ dis, const float* __restrict__ bias, OT* __restrict__ out, int n) {
  constexpr int VEC = F / 64;
  int wid = (int)((blockIdx.x * blockDim.x + threadIdx.x) >> 6);
  int lane = threadIdx.x & 63;
  if (wid >= n) return;
  int node = __builtin_amdgcn_readfirstlane(wid);
  float dd = dis[node];
  float acc[VEC];
  {
    const float* hs = H + (size_t)node * F + lane * VEC;
    if constexpr (VEC == 4) {
      float4 h = *(const float4*)hs;
      acc[0] = h.x * dd * dd; acc[1] = h.y * dd * dd; acc[2] = h.z * dd * dd; acc[3] = h.w * dd * dd;
    } else if constexpr (VEC == 2) {
      float2 h = *(const float2*)hs;
      acc[0] = h.x * dd * dd; acc[1] = h.y * dd * dd;
    } else {
      acc[0] = hs[0] * dd * dd;
    }
  }
  int beg = rowptr[node], end = rowptr[node + 1];
  for (int e = beg; e < end; ++e) {
    int s = col[e];
    float w = dis[s] * dd;
    const float* hs = H + (size_t)s * F + lane * VEC;
    if constexpr (VEC == 4) {
      float4 h = *(const float4*)hs;
      acc[0] = fmaf(h.x, w, acc[0]); acc[1] = fmaf(h.y, w, acc[1]);
      acc[2] = fmaf(h.z, w, acc[2]); acc[3] = fmaf(h.w, w, acc[3]);
    } else if constexpr (VEC == 2) {
      float2 h = *(const float2*)hs;
      acc[0] = fmaf(h.x, w, acc[0]); acc[1] = fmaf(h.y, w, acc[1]);
    } else {
      acc[0] = fmaf(hs[0], w, acc[0]);
    }
  }
  OT* o = out + (size_t)node * F + lane * VEC;
#pragma unroll
  for (int i = 0; i < VEC; ++i) {
    float v = acc[i];
    if constexpr (EPI) v = tanhf(v + bias[lane * VEC + i]);
    o[i] = (OT)v;
  }
}

__global__ __launch_bounds__(128) void crow_kernel(const unsigned* __restrict__ maxkey,
                                                   const float* __restrict__ W7top,
                                                   float* __restrict__ crow) {
  int j = threadIdx.x;  // 128
  float s = 0.f;
  for (int f = 0; f < 256; ++f) s = fmaf(dec_key(maxkey[f]), W7top[f * 128 + j], s);
  crow[j] = s;
}

// ---------------- launch ----------------
extern "C" void kernel_launch(void* const* d_in, const int* in_sizes, int n_in,
                              void* d_out, int out_size, void* d_ws, size_t ws_size,
                              hipStream_t stream) {
  const float* x  = (const float*)d_in[0];
  const int* ei   = (const int*)d_in[1];
  const int* srcp = ei;
  const int* dstp = ei + EE;
  const float* W1 = (const float*)d_in[3];
  const float* b1 = (const float*)d_in[4];
  const float* W2 = (const float*)d_in[5];
  const float* b2 = (const float*)d_in[6];
  const float* W3 = (const float*)d_in[7];
  const float* b3 = (const float*)d_in[8];
  const float* W4 = (const float*)d_in[9];
  const float* b4 = (const float*)d_in[10];
  const float* W7 = (const float*)d_in[11];
  const float* b7 = (const float*)d_in[12];
  float* out = (float*)d_out;

  char* p = (char*)d_ws;
  auto alloc = [&](size_t bytes) -> void* {
    void* r = (void*)p;
    p += (bytes + 255) & ~(size_t)255;
    return r;
  };
  float*  H   = (float*)alloc((size_t)NN * 128 * 4);   // stage-5 f32 buffer
  float*  A   = (float*)alloc((size_t)NN * 128 * 4);   // t1 / t3 (f32)
  __bf16* Hb  = (__bf16*)alloc((size_t)NN * 128 * 2);  // agg output for MFMA stages
  __bf16* Bb  = (__bf16*)alloc((size_t)NN * 256 * 2);  // i2 (bf16)
  float*  AX  = (float*)alloc((size_t)NN * 64 * 4);    // agg(x), reused 2x
  __bf16* W2t = (__bf16*)alloc((size_t)256 * 128 * 2);
  __bf16* W4t = (__bf16*)alloc((size_t)256 * 128 * 2);
  __bf16* W7t = (__bf16*)alloc((size_t)128 * 256 * 2);
  float* dis = (float*)alloc((size_t)NN * 4);
  int* cnt = (int*)alloc((size_t)NN * 4);
  int* cursor = (int*)alloc((size_t)NN * 4);
  int* rowptr = (int*)alloc((size_t)(NN + 1) * 4);
  int* col = (int*)alloc((size_t)EE * 4);
  int* bsum = (int*)alloc(64 * 4);
  unsigned* maxkey = (unsigned*)alloc(256 * 4);
  float* crow = (float*)alloc(128 * 4);

  hipMemsetAsync(cnt, 0, (size_t)NN * 4, stream);
  hipMemsetAsync(cursor, 0, (size_t)NN * 4, stream);
  hipMemsetAsync(maxkey, 0, 256 * 4, stream);

  int eb = (EE + 255) / 256;
  int nb = (NN + 255) / 256;
  int nchunks = (NN + SCAN_CHUNK - 1) / SCAN_CHUNK;
  count_kernel<<<eb, 256, 0, stream>>>(dstp, cnt, EE);
  dis_kernel<<<nb, 256, 0, stream>>>(cnt, dis, NN);
  scan1_kernel<<<nchunks, 256, 0, stream>>>(cnt, rowptr, bsum, NN);
  scan2_kernel<<<1, 64, 0, stream>>>(bsum, nchunks);
  scan3_kernel<<<nb, 256, 0, stream>>>(rowptr, bsum, NN, EE);
  fill_kernel<<<eb, 256, 0, stream>>>(srcp, dstp, rowptr, cursor, col, EE);

  // weight prep (bf16, transposed) — tiny one-shot work
  wcvt_kernel<<<(256 * 128 + 255) / 256, 256, 0, stream>>>(W2, W2t, 128, 256);
  wcvt_kernel<<<(256 * 128 + 255) / 256, 256, 0, stream>>>(W4, W4t, 128, 256);
  wcvt_kernel<<<(128 * 256 + 255) / 256, 256, 0, stream>>>(W7 + 256 * 128, W7t, 256, 128);

  dim3 gB(256);
  int mrows = (NN + BM - 1) / BM;   // 782 (f32 gemm)
  int mrowsT = (NN + TM - 1) / TM;  // 391 (mfma gemm)
  int aggB = (NN + 3) / 4;          // 1 wave/node

  // AX = agg(x)  [N,64] — shared by stages 1, 3
  agg_kernel<64, false, float><<<aggB, gB, 0, stream>>>(x, rowptr, col, dis, nullptr, AX, NN);
  // stage 1: t1 = tanh(AX@W1 + b1) -> A  [N,128]  (f32, K=64)
  gemm_f32<<<dim3(mrows, 2), gB, 0, stream>>>(AX, W1, A, NN, 64, 128, b1, 0, 1);
  // stage 2: Hb = agg(t1) (bf16); colmax(tanh(Hb@W2+b2)) -> maxkey. NO store (t2 dead otherwise).
  agg_kernel<128, false, __bf16><<<aggB, gB, 0, stream>>>(A, rowptr, col, dis, nullptr, Hb, NN);
  gemm_mfma<<<dim3(mrowsT, 4), gB, 0, stream>>>(Hb, W2t, nullptr, nullptr, NN, 128, 256, b2, 1, maxkey);
  // stage 3: t3 = tanh(AX@W3 + b3) -> A  (f32, K=64)
  gemm_f32<<<dim3(mrows, 2), gB, 0, stream>>>(AX, W3, A, NN, 64, 128, b3, 0, 1);
  // stage 4: Hb = agg(t3) (bf16); i2 = tanh(Hb@W4+b4) -> Bb (bf16)
  agg_kernel<128, false, __bf16><<<aggB, gB, 0, stream>>>(A, rowptr, col, dis, nullptr, Hb, NN);
  gemm_mfma<<<dim3(mrowsT, 4), gB, 0, stream>>>(Hb, W4t, nullptr, Bb, NN, 128, 256, b4, 1, nullptr);
  // stage 5: H = crow + i2@W7b (MFMA) ; H += x@W7c (f32) ; out = tanh(agg(H)+b7)
  crow_kernel<<<1, 128, 0, stream>>>(maxkey, W7, crow);
  gemm_mfma<<<dim3(mrowsT, 2), gB, 0, stream>>>(Bb, W7t, H, nullptr, NN, 256, 128, crow, 0, nullptr);
  gemm_f32<<<dim3(mrows, 2), gB, 0, stream>>>(x, W7 + 512 * 128, H, NN, 64, 128, nullptr, 1, 0);
  agg_kernel<128, true, float><<<aggB, gB, 0, stream>>>(H, rowptr, col, dis, b7, out, NN);
}

// Round 13
// 488.142 us; speedup vs baseline: 1.0128x; 1.0128x over previous
//
#include <hip/hip_runtime.h>
#include <hip/hip_bf16.h>
#include <cstdint>
#include <cstddef>

#define NN 50000
#define EE 400000

typedef __attribute__((ext_vector_type(8))) __bf16 bf16x8;
typedef __attribute__((ext_vector_type(4))) float f32x4;

// ---------------- helpers ----------------
static __device__ __forceinline__ float dec_key(unsigned k) {
  return (k & 0x80000000u) ? __uint_as_float(k & 0x7fffffffu) : __uint_as_float(~k);
}
static __device__ __forceinline__ unsigned enc_key(float f) {
  unsigned b = __float_as_uint(f);
  return (f >= 0.f) ? (b | 0x80000000u) : ~b;
}

// ---------------- CSR build ----------------
__global__ void count_kernel(const int* __restrict__ dst, int* __restrict__ cnt, int e) {
  int i = blockIdx.x * blockDim.x + threadIdx.x;
  if (i < e) atomicAdd(&cnt[dst[i]], 1);
}

__global__ void dis_kernel(const int* __restrict__ cnt, float* __restrict__ dis, int n) {
  int i = blockIdx.x * blockDim.x + threadIdx.x;
  if (i < n) dis[i] = rsqrtf((float)cnt[i] + 1.0f);
}

#define SCAN_CHUNK 1024
__global__ __launch_bounds__(256) void scan1_kernel(const int* __restrict__ cnt,
                                                    int* __restrict__ rowptr,
                                                    int* __restrict__ bsum, int n) {
  int b = blockIdx.x;
  int base = b * SCAN_CHUNK;
  int t = threadIdx.x;
  int v[4];
  int s = 0;
#pragma unroll
  for (int i = 0; i < 4; ++i) {
    int idx = base + t * 4 + i;
    v[i] = (idx < n) ? cnt[idx] : 0;
    s += v[i];
  }
  int lane = t & 63, w = t >> 6;
  int inc = s;
#pragma unroll
  for (int off = 1; off < 64; off <<= 1) {
    int o = __shfl_up(inc, off, 64);
    if (lane >= off) inc += o;
  }
  __shared__ int wsum[4];
  if (lane == 63) wsum[w] = inc;
  __syncthreads();
  int woff = 0;
  for (int i = 0; i < w; ++i) woff += wsum[i];
  int run = woff + inc - s;
#pragma unroll
  for (int i = 0; i < 4; ++i) {
    int idx = base + t * 4 + i;
    if (idx < n) rowptr[idx] = run;
    run += v[i];
  }
  if (t == 255) bsum[b] = woff + inc;
}

__global__ void scan2_kernel(int* __restrict__ bsum, int nb) {
  int t = threadIdx.x;
  int v = (t < nb) ? bsum[t] : 0;
  int s = v;
#pragma unroll
  for (int off = 1; off < 64; off <<= 1) {
    int o = __shfl_up(s, off, 64);
    if (t >= off) s += o;
  }
  if (t < nb) bsum[t] = s - v;
}

__global__ __launch_bounds__(256) void scan3_kernel(int* __restrict__ rowptr,
                                                    const int* __restrict__ bsum, int n, int total) {
  int i = blockIdx.x * blockDim.x + threadIdx.x;
  if (i < n) rowptr[i] += bsum[i >> 10];
  if (i == 0) rowptr[n] = total;
}

__global__ void fill_kernel(const int* __restrict__ src, const int* __restrict__ dst,
                            const int* __restrict__ rowptr, int* __restrict__ cursor,
                            int* __restrict__ col, int e) {
  int i = blockIdx.x * blockDim.x + threadIdx.x;
  if (i < e) {
    int d = dst[i];
    int p = atomicAdd(&cursor[d], 1);
    col[rowptr[d] + p] = src[i];
  }
}

// ---------------- weight cvt+transpose: Wt[n][k] = bf16(W[k][n]) ----------------
__global__ __launch_bounds__(256) void wcvt_kernel(const float* __restrict__ W,
                                                   __bf16* __restrict__ Wt, int K, int Nout) {
  int idx = blockIdx.x * blockDim.x + threadIdx.x;
  if (idx < K * Nout) {
    int n = idx / K, k = idx - n * K;
    Wt[idx] = (__bf16)W[(size_t)k * Nout + n];
  }
}

// ---------------- concat [W1|W3] -> Wcat[64][256] f32, bcat[256] ----------------
__global__ __launch_bounds__(256) void wcat_kernel(const float* __restrict__ W1,
                                                   const float* __restrict__ W3,
                                                   const float* __restrict__ b1,
                                                   const float* __restrict__ b3,
                                                   float* __restrict__ Wcat,
                                                   float* __restrict__ bcat) {
  int idx = blockIdx.x * blockDim.x + threadIdx.x;
  if (idx < 64 * 256) {
    int k = idx >> 8, j = idx & 255;
    Wcat[idx] = (j < 128) ? W1[k * 128 + j] : W3[k * 128 + (j - 128)];
  }
  if (idx < 256) bcat[idx] = (idx < 128) ? b1[idx] : b3[idx - 128];
}

// ---------------- f32 GEMM: C = A@W, fused epilogue ----------------
#define BM 64
#define BN 64
#define BK 16

__global__ __launch_bounds__(256) void gemm_f32(
    const float* __restrict__ A, const float* __restrict__ W, float* __restrict__ C,
    int M, int K, int Nout, const float* __restrict__ colAdd, int accumulate, int doTanh) {
  __shared__ float As[BK][BM + 4];
  __shared__ float Ws[BK][BN];
  int tid = threadIdx.x;
  int row0 = blockIdx.x * BM;
  int col0 = blockIdx.y * BN;
  int tx = tid & 15;
  int ty = tid >> 4;
  float acc[4][4] = {};
  for (int k0 = 0; k0 < K; k0 += BK) {
#pragma unroll
    for (int i = 0; i < 4; ++i) {
      int idx = tid + i * 256;
      int r = idx >> 4, c = idx & 15;
      int gr = row0 + r;
      float v = (gr < M) ? A[(size_t)gr * K + k0 + c] : 0.f;
      As[c][r] = v;
    }
#pragma unroll
    for (int i = 0; i < 4; ++i) {
      int idx = tid + i * 256;
      int r = idx >> 6, c = idx & 63;
      Ws[r][c] = W[(size_t)(k0 + r) * Nout + col0 + c];
    }
    __syncthreads();
#pragma unroll
    for (int kk = 0; kk < BK; ++kk) {
      float4 av = *(const float4*)&As[kk][ty * 4];
      float4 wv = *(const float4*)&Ws[kk][tx * 4];
      float a[4] = {av.x, av.y, av.z, av.w};
      float w[4] = {wv.x, wv.y, wv.z, wv.w};
#pragma unroll
      for (int i = 0; i < 4; ++i)
#pragma unroll
        for (int j = 0; j < 4; ++j) acc[i][j] = fmaf(a[i], w[j], acc[i][j]);
    }
    __syncthreads();
  }
#pragma unroll
  for (int i = 0; i < 4; ++i) {
    int gr = row0 + ty * 4 + i;
    if (gr >= M) continue;
#pragma unroll
    for (int j = 0; j < 4; ++j) {
      int gc = col0 + tx * 4 + j;
      size_t idx = (size_t)gr * Nout + gc;
      float v = acc[i][j];
      if (colAdd) v += colAdd[gc];
      if (accumulate) v += C[idx];
      if (doTanh) v = tanhf(v);
      C[idx] = v;
    }
  }
}

// ---------------- bf16 MFMA GEMM (LDS-staged, r11 structure + lda) ----------------
// A[M,*](bf16, row stride lda) @ Wt[Nout,K](bf16 pre-transposed). 128x64 tile,
// BK=64, 4 waves each 64x32, XOR-swizzled LDS, staging = pure 16B copies.
// Optional outputs: Cf (f32), Ch (bf16); optional fused per-column max of the
// (possibly tanh'd) outputs via encoded atomicMax (stage-2: raw z, no tanh, no
// stores — colmax only; tanh applied later to the 256 maxima by monotonicity).
#define TM 128
#define TN 64
#define TK 64

__global__ __launch_bounds__(256) void gemm_mfma(
    const __bf16* __restrict__ A, int lda, const __bf16* __restrict__ Wt,
    float* __restrict__ Cf, __bf16* __restrict__ Ch,
    int M, int K, int Nout, const float* __restrict__ colAdd, int doTanh,
    unsigned* __restrict__ colmaxOut) {
  __shared__ char lds[(TM * TK + TN * TK) * 2];  // As bf16[128][64], Bt bf16[64][64]
  char* AsB = lds;
  char* BtB = lds + TM * TK * 2;
  int tid = threadIdx.x;
  int row0 = blockIdx.x * TM;
  int col0 = blockIdx.y * TN;
  int w = tid >> 6, l = tid & 63;
  int lr = l & 15, lh = l >> 4;
  int wmB = (w >> 1) * 64;  // wave row base within tile
  int wnB = (w & 1) * 32;   // wave col base within tile
  f32x4 acc[4][2] = {};
  for (int k0 = 0; k0 < K; k0 += TK) {
    if (k0) __syncthreads();
    // stage A: 4 octets (16B) per thread, swz byte ^= (row&7)<<4
#pragma unroll
    for (int i = 0; i < 4; ++i) {
      int id = tid + i * 256;
      int r = id >> 3, oc = id & 7;
      int gr = row0 + r;
      bf16x8 sv;
      if (gr < M) sv = *(const bf16x8*)(A + (size_t)gr * lda + k0 + oc * 8);
      else sv = bf16x8{};
      int byte = (r * 128 + oc * 16) ^ ((r & 7) << 4);
      *(bf16x8*)(AsB + byte) = sv;
    }
    // stage Bt: 2 octets per thread from pre-transposed bf16 weights
#pragma unroll
    for (int i = 0; i < 2; ++i) {
      int id = tid + i * 256;
      int c = id >> 3, oc = id & 7;
      bf16x8 sv = *(const bf16x8*)(Wt + (size_t)(col0 + c) * K + k0 + oc * 8);
      int byte = (c * 128 + oc * 16) ^ ((c & 7) << 4);
      *(bf16x8*)(BtB + byte) = sv;
    }
    __syncthreads();
    // 2 MFMA k-steps of 32
#pragma unroll
    for (int s = 0; s < 2; ++s) {
      bf16x8 af[4], bfr[2];
#pragma unroll
      for (int mi = 0; mi < 4; ++mi) {
        int r = wmB + mi * 16 + lr;
        int byte = (r * 128 + (s * 32 + lh * 8) * 2) ^ ((r & 7) << 4);
        af[mi] = *(const bf16x8*)(AsB + byte);
      }
#pragma unroll
      for (int ni = 0; ni < 2; ++ni) {
        int c = wnB + ni * 16 + lr;
        int byte = (c * 128 + (s * 32 + lh * 8) * 2) ^ ((c & 7) << 4);
        bfr[ni] = *(const bf16x8*)(BtB + byte);
      }
#pragma unroll
      for (int mi = 0; mi < 4; ++mi)
#pragma unroll
        for (int ni = 0; ni < 2; ++ni)
          acc[mi][ni] =
              __builtin_amdgcn_mfma_f32_16x16x32_bf16(af[mi], bfr[ni], acc[mi][ni], 0, 0, 0);
    }
  }
  // epilogue: C/D layout col = lane&15, row = (lane>>4)*4 + reg
  float cmax[2] = {-3.0e38f, -3.0e38f};  // raw-z colmax: sentinel below any finite z
#pragma unroll
  for (int mi = 0; mi < 4; ++mi) {
#pragma unroll
    for (int ni = 0; ni < 2; ++ni) {
#pragma unroll
      for (int r = 0; r < 4; ++r) {
        int gr = row0 + wmB + mi * 16 + lh * 4 + r;
        if (gr >= M) continue;
        int gc = col0 + wnB + ni * 16 + lr;
        size_t idx = (size_t)gr * Nout + gc;
        float v = acc[mi][ni][r];
        if (colAdd) v += colAdd[gc];
        if (doTanh) v = tanhf(v);
        if (colmaxOut) cmax[ni] = fmaxf(cmax[ni], v);
        if (Cf) Cf[idx] = v;
        if (Ch) Ch[idx] = (__bf16)v;
      }
    }
  }
  if (colmaxOut) {
    // lanes {lr, lr+16, lr+32, lr+48} share a column; combine then 1 atomic per col per wave
#pragma unroll
    for (int ni = 0; ni < 2; ++ni) {
      float m = cmax[ni];
      m = fmaxf(m, __shfl_xor(m, 16));
      m = fmaxf(m, __shfl_xor(m, 32));
      if (lh == 0) {
        int gc = col0 + wnB + ni * 16 + lr;
        atomicMax(&colmaxOut[gc], enc_key(m));
      }
    }
  }
}

// ---------------- aggregation: out[d] = sum_{s in N(d)} H[s]*dis[s]*dis[d] + H[d]*dis[d]^2 ----------------
template <int F, bool EPI, typename OT>
__global__ __launch_bounds__(256) void agg_kernel(
    const float* __restrict__ H, const int* __restrict__ rowptr, const int* __restrict__ col,
    const float* __restrict__ dis, const float* __restrict__ bias, OT* __restrict__ out, int n) {
  constexpr int VEC = F / 64;
  int wid = (int)((blockIdx.x * blockDim.x + threadIdx.x) >> 6);
  int lane = threadIdx.x & 63;
  if (wid >= n) return;
  int node = __builtin_amdgcn_readfirstlane(wid);
  float dd = dis[node];
  float acc[VEC];
  {
    const float* hs = H + (size_t)node * F + lane * VEC;
    if constexpr (VEC == 4) {
      float4 h = *(const float4*)hs;
      acc[0] = h.x * dd * dd; acc[1] = h.y * dd * dd; acc[2] = h.z * dd * dd; acc[3] = h.w * dd * dd;
    } else if constexpr (VEC == 2) {
      float2 h = *(const float2*)hs;
      acc[0] = h.x * dd * dd; acc[1] = h.y * dd * dd;
    } else {
      acc[0] = hs[0] * dd * dd;
    }
  }
  int beg = rowptr[node], end = rowptr[node + 1];
  for (int e = beg; e < end; ++e) {
    int s = col[e];
    float w = dis[s] * dd;
    const float* hs = H + (size_t)s * F + lane * VEC;
    if constexpr (VEC == 4) {
      float4 h = *(const float4*)hs;
      acc[0] = fmaf(h.x, w, acc[0]); acc[1] = fmaf(h.y, w, acc[1]);
      acc[2] = fmaf(h.z, w, acc[2]); acc[3] = fmaf(h.w, w, acc[3]);
    } else if constexpr (VEC == 2) {
      float2 h = *(const float2*)hs;
      acc[0] = fmaf(h.x, w, acc[0]); acc[1] = fmaf(h.y, w, acc[1]);
    } else {
      acc[0] = fmaf(hs[0], w, acc[0]);
    }
  }
  OT* o = out + (size_t)node * F + lane * VEC;
#pragma unroll
  for (int i = 0; i < VEC; ++i) {
    float v = acc[i];
    if constexpr (EPI) v = tanhf(v + bias[lane * VEC + i]);
    o[i] = (OT)v;
  }
}

// crow[j] = sum_f tanh(maxz[f]) * W7top[f][j]  (tanh moved here by monotonicity)
__global__ __launch_bounds__(128) void crow_kernel(const unsigned* __restrict__ maxkey,
                                                   const float* __restrict__ W7top,
                                                   float* __restrict__ crow) {
  int j = threadIdx.x;  // 128
  float s = 0.f;
  for (int f = 0; f < 256; ++f) s = fmaf(tanhf(dec_key(maxkey[f])), W7top[f * 128 + j], s);
  crow[j] = s;
}

// ---------------- launch ----------------
extern "C" void kernel_launch(void* const* d_in, const int* in_sizes, int n_in,
                              void* d_out, int out_size, void* d_ws, size_t ws_size,
                              hipStream_t stream) {
  const float* x  = (const float*)d_in[0];
  const int* ei   = (const int*)d_in[1];
  const int* srcp = ei;
  const int* dstp = ei + EE;
  const float* W1 = (const float*)d_in[3];
  const float* b1 = (const float*)d_in[4];
  const float* W2 = (const float*)d_in[5];
  const float* b2 = (const float*)d_in[6];
  const float* W3 = (const float*)d_in[7];
  const float* b3 = (const float*)d_in[8];
  const float* W4 = (const float*)d_in[9];
  const float* b4 = (const float*)d_in[10];
  const float* W7 = (const float*)d_in[11];
  const float* b7 = (const float*)d_in[12];
  float* out = (float*)d_out;

  char* p = (char*)d_ws;
  auto alloc = [&](size_t bytes) -> void* {
    void* r = (void*)p;
    p += (bytes + 255) & ~(size_t)255;
    return r;
  };
  float*  T13  = (float*)alloc((size_t)NN * 256 * 4);   // [t1|t3] f32
  float*  H    = (float*)alloc((size_t)NN * 128 * 4);   // stage-5 f32 buffer
  __bf16* Hb13 = (__bf16*)alloc((size_t)NN * 256 * 2);  // agg([t1|t3]) bf16
  __bf16* Bb   = (__bf16*)alloc((size_t)NN * 256 * 2);  // i2 (bf16)
  float*  AX   = (float*)alloc((size_t)NN * 64 * 4);    // agg(x)
  __bf16* W2t  = (__bf16*)alloc((size_t)256 * 128 * 2);
  __bf16* W4t  = (__bf16*)alloc((size_t)256 * 128 * 2);
  __bf16* W7t  = (__bf16*)alloc((size_t)128 * 256 * 2);
  float*  Wcat = (float*)alloc((size_t)64 * 256 * 4);
  float*  bcat = (float*)alloc(256 * 4);
  float* dis = (float*)alloc((size_t)NN * 4);
  int* cnt = (int*)alloc((size_t)NN * 4);
  int* cursor = (int*)alloc((size_t)NN * 4);
  int* rowptr = (int*)alloc((size_t)(NN + 1) * 4);
  int* col = (int*)alloc((size_t)EE * 4);
  int* bsum = (int*)alloc(64 * 4);
  unsigned* maxkey = (unsigned*)alloc(256 * 4);
  float* crow = (float*)alloc(128 * 4);

  hipMemsetAsync(cnt, 0, (size_t)NN * 4, stream);
  hipMemsetAsync(cursor, 0, (size_t)NN * 4, stream);
  hipMemsetAsync(maxkey, 0, 256 * 4, stream);

  int eb = (EE + 255) / 256;
  int nb = (NN + 255) / 256;
  int nchunks = (NN + SCAN_CHUNK - 1) / SCAN_CHUNK;
  count_kernel<<<eb, 256, 0, stream>>>(dstp, cnt, EE);
  dis_kernel<<<nb, 256, 0, stream>>>(cnt, dis, NN);
  scan1_kernel<<<nchunks, 256, 0, stream>>>(cnt, rowptr, bsum, NN);
  scan2_kernel<<<1, 64, 0, stream>>>(bsum, nchunks);
  scan3_kernel<<<nb, 256, 0, stream>>>(rowptr, bsum, NN, EE);
  fill_kernel<<<eb, 256, 0, stream>>>(srcp, dstp, rowptr, cursor, col, EE);

  // weight prep — tiny one-shot work
  wcvt_kernel<<<(256 * 128 + 255) / 256, 256, 0, stream>>>(W2, W2t, 128, 256);
  wcvt_kernel<<<(256 * 128 + 255) / 256, 256, 0, stream>>>(W4, W4t, 128, 256);
  wcvt_kernel<<<(128 * 256 + 255) / 256, 256, 0, stream>>>(W7 + 256 * 128, W7t, 256, 128);
  wcat_kernel<<<(64 * 256 + 255) / 256, 256, 0, stream>>>(W1, W3, b1, b3, Wcat, bcat);

  dim3 gB(256);
  int mrows = (NN + BM - 1) / BM;   // 782 (f32 gemm)
  int mrowsT = (NN + TM - 1) / TM;  // 391 (mfma gemm)
  int aggB = (NN + 3) / 4;          // 1 wave/node

  // AX = agg(x)  [N,64]
  agg_kernel<64, false, float><<<aggB, gB, 0, stream>>>(x, rowptr, col, dis, nullptr, AX, NN);
  // merged stage 1+3: [t1|t3] = tanh(AX@[W1|W3] + [b1|b3]) -> T13  [N,256] (f32, K=64)
  gemm_f32<<<dim3(mrows, 4), gB, 0, stream>>>(AX, Wcat, T13, NN, 64, 256, bcat, 0, 1);
  // merged agg: Hb13 = agg(T13) (bf16)  [N,256]
  agg_kernel<256, false, __bf16><<<aggB, gB, 0, stream>>>(T13, rowptr, col, dis, nullptr, Hb13, NN);
  // stage 2: colmax over raw z = Hb13[:,0:128]@W2 + b2 (tanh deferred to crow; no stores)
  gemm_mfma<<<dim3(mrowsT, 4), gB, 0, stream>>>(Hb13, 256, W2t, nullptr, nullptr, NN, 128, 256, b2, 0, maxkey);
  // stage 4: i2 = tanh(Hb13[:,128:256]@W4 + b4) -> Bb (bf16)
  gemm_mfma<<<dim3(mrowsT, 4), gB, 0, stream>>>(Hb13 + 128, 256, W4t, nullptr, Bb, NN, 128, 256, b4, 1, nullptr);
  // stage 5: H = crow + i2@W7b (MFMA) ; H += x@W7c (f32) ; out = tanh(agg(H)+b7)
  crow_kernel<<<1, 128, 0, stream>>>(maxkey, W7, crow);
  gemm_mfma<<<dim3(mrowsT, 2), gB, 0, stream>>>(Bb, 256, W7t, H, nullptr, NN, 256, 128, crow, 0, nullptr);
  gemm_f32<<<dim3(mrows, 2), gB, 0, stream>>>(x, W7 + 512 * 128, H, NN, 64, 128, nullptr, 1, 0);
  agg_kernel<128, true, float><<<aggB, gB, 0, stream>>>(H, rowptr, col, dis, b7, out, NN);
}

// Round 14
// 457.413 us; speedup vs baseline: 1.0809x; 1.0672x over previous
//
#include <hip/hip_runtime.h>
#include <hip/hip_bf16.h>
#include <cstdint>
#include <cstddef>

#define NN 50000
#define EE 400000

typedef __attribute__((ext_vector_type(8))) __bf16 bf16x8;
typedef __attribute__((ext_vector_type(4))) __bf16 bf16x4;
typedef __attribute__((ext_vector_type(2))) __bf16 bf16x2;
typedef __attribute__((ext_vector_type(4))) float f32x4;

// ---------------- helpers ----------------
static __device__ __forceinline__ float dec_key(unsigned k) {
  return (k & 0x80000000u) ? __uint_as_float(k & 0x7fffffffu) : __uint_as_float(~k);
}
static __device__ __forceinline__ unsigned enc_key(float f) {
  unsigned b = __float_as_uint(f);
  return (f >= 0.f) ? (b | 0x80000000u) : ~b;
}

// ---------------- CSR build ----------------
__global__ void count_kernel(const int* __restrict__ dst, int* __restrict__ cnt, int e) {
  int i = blockIdx.x * blockDim.x + threadIdx.x;
  if (i < e) atomicAdd(&cnt[dst[i]], 1);
}

__global__ void dis_kernel(const int* __restrict__ cnt, float* __restrict__ dis, int n) {
  int i = blockIdx.x * blockDim.x + threadIdx.x;
  if (i < n) dis[i] = rsqrtf((float)cnt[i] + 1.0f);
}

#define SCAN_CHUNK 1024
__global__ __launch_bounds__(256) void scan1_kernel(const int* __restrict__ cnt,
                                                    int* __restrict__ rowptr,
                                                    int* __restrict__ bsum, int n) {
  int b = blockIdx.x;
  int base = b * SCAN_CHUNK;
  int t = threadIdx.x;
  int v[4];
  int s = 0;
#pragma unroll
  for (int i = 0; i < 4; ++i) {
    int idx = base + t * 4 + i;
    v[i] = (idx < n) ? cnt[idx] : 0;
    s += v[i];
  }
  int lane = t & 63, w = t >> 6;
  int inc = s;
#pragma unroll
  for (int off = 1; off < 64; off <<= 1) {
    int o = __shfl_up(inc, off, 64);
    if (lane >= off) inc += o;
  }
  __shared__ int wsum[4];
  if (lane == 63) wsum[w] = inc;
  __syncthreads();
  int woff = 0;
  for (int i = 0; i < w; ++i) woff += wsum[i];
  int run = woff + inc - s;
#pragma unroll
  for (int i = 0; i < 4; ++i) {
    int idx = base + t * 4 + i;
    if (idx < n) rowptr[idx] = run;
    run += v[i];
  }
  if (t == 255) bsum[b] = woff + inc;
}

__global__ void scan2_kernel(int* __restrict__ bsum, int nb) {
  int t = threadIdx.x;
  int v = (t < nb) ? bsum[t] : 0;
  int s = v;
#pragma unroll
  for (int off = 1; off < 64; off <<= 1) {
    int o = __shfl_up(s, off, 64);
    if (t >= off) s += o;
  }
  if (t < nb) bsum[t] = s - v;
}

__global__ __launch_bounds__(256) void scan3_kernel(int* __restrict__ rowptr,
                                                    const int* __restrict__ bsum, int n, int total) {
  int i = blockIdx.x * blockDim.x + threadIdx.x;
  if (i < n) rowptr[i] += bsum[i >> 10];
  if (i == 0) rowptr[n] = total;
}

__global__ void fill_kernel(const int* __restrict__ src, const int* __restrict__ dst,
                            const int* __restrict__ rowptr, int* __restrict__ cursor,
                            int* __restrict__ col, int e) {
  int i = blockIdx.x * blockDim.x + threadIdx.x;
  if (i < e) {
    int d = dst[i];
    int p = atomicAdd(&cursor[d], 1);
    col[rowptr[d] + p] = src[i];
  }
}

// ---------------- weight cvt+transpose: Wt[n][k] = bf16(W[k][n]) ----------------
__global__ __launch_bounds__(256) void wcvt_kernel(const float* __restrict__ W,
                                                   __bf16* __restrict__ Wt, int K, int Nout) {
  int idx = blockIdx.x * blockDim.x + threadIdx.x;
  if (idx < K * Nout) {
    int n = idx / K, k = idx - n * K;
    Wt[idx] = (__bf16)W[(size_t)k * Nout + n];
  }
}

// ---------------- concat [W1|W3] -> Wcat[64][256] f32, bcat[256] ----------------
__global__ __launch_bounds__(256) void wcat_kernel(const float* __restrict__ W1,
                                                   const float* __restrict__ W3,
                                                   const float* __restrict__ b1,
                                                   const float* __restrict__ b3,
                                                   float* __restrict__ Wcat,
                                                   float* __restrict__ bcat) {
  int idx = blockIdx.x * blockDim.x + threadIdx.x;
  if (idx < 64 * 256) {
    int k = idx >> 8, j = idx & 255;
    Wcat[idx] = (j < 128) ? W1[k * 128 + j] : W3[k * 128 + (j - 128)];
  }
  if (idx < 256) bcat[idx] = (idx < 128) ? b1[idx] : b3[idx - 128];
}

// ---------------- f32 GEMM: C = A@W, fused epilogue; output type templated ----------------
#define BM 64
#define BN 64
#define BK 16

template <typename OT>
__global__ __launch_bounds__(256) void gemm_f32(
    const float* __restrict__ A, const float* __restrict__ W, OT* __restrict__ C,
    int M, int K, int Nout, const float* __restrict__ colAdd, int accumulate, int doTanh) {
  __shared__ float As[BK][BM + 4];
  __shared__ float Ws[BK][BN];
  int tid = threadIdx.x;
  int row0 = blockIdx.x * BM;
  int col0 = blockIdx.y * BN;
  int tx = tid & 15;
  int ty = tid >> 4;
  float acc[4][4] = {};
  for (int k0 = 0; k0 < K; k0 += BK) {
#pragma unroll
    for (int i = 0; i < 4; ++i) {
      int idx = tid + i * 256;
      int r = idx >> 4, c = idx & 15;
      int gr = row0 + r;
      float v = (gr < M) ? A[(size_t)gr * K + k0 + c] : 0.f;
      As[c][r] = v;
    }
#pragma unroll
    for (int i = 0; i < 4; ++i) {
      int idx = tid + i * 256;
      int r = idx >> 6, c = idx & 63;
      Ws[r][c] = W[(size_t)(k0 + r) * Nout + col0 + c];
    }
    __syncthreads();
#pragma unroll
    for (int kk = 0; kk < BK; ++kk) {
      float4 av = *(const float4*)&As[kk][ty * 4];
      float4 wv = *(const float4*)&Ws[kk][tx * 4];
      float a[4] = {av.x, av.y, av.z, av.w};
      float w[4] = {wv.x, wv.y, wv.z, wv.w};
#pragma unroll
      for (int i = 0; i < 4; ++i)
#pragma unroll
        for (int j = 0; j < 4; ++j) acc[i][j] = fmaf(a[i], w[j], acc[i][j]);
    }
    __syncthreads();
  }
#pragma unroll
  for (int i = 0; i < 4; ++i) {
    int gr = row0 + ty * 4 + i;
    if (gr >= M) continue;
#pragma unroll
    for (int j = 0; j < 4; ++j) {
      int gc = col0 + tx * 4 + j;
      size_t idx = (size_t)gr * Nout + gc;
      float v = acc[i][j];
      if (colAdd) v += colAdd[gc];
      if (accumulate) v += (float)C[idx];
      if (doTanh) v = tanhf(v);
      C[idx] = (OT)v;
    }
  }
}

// ---------------- bf16 MFMA GEMM (LDS-staged + lda) ----------------
#define TM 128
#define TN 64
#define TK 64

__global__ __launch_bounds__(256) void gemm_mfma(
    const __bf16* __restrict__ A, int lda, const __bf16* __restrict__ Wt,
    float* __restrict__ Cf, __bf16* __restrict__ Ch,
    int M, int K, int Nout, const float* __restrict__ colAdd, int doTanh,
    unsigned* __restrict__ colmaxOut) {
  __shared__ char lds[(TM * TK + TN * TK) * 2];  // As bf16[128][64], Bt bf16[64][64]
  char* AsB = lds;
  char* BtB = lds + TM * TK * 2;
  int tid = threadIdx.x;
  int row0 = blockIdx.x * TM;
  int col0 = blockIdx.y * TN;
  int w = tid >> 6, l = tid & 63;
  int lr = l & 15, lh = l >> 4;
  int wmB = (w >> 1) * 64;  // wave row base within tile
  int wnB = (w & 1) * 32;   // wave col base within tile
  f32x4 acc[4][2] = {};
  for (int k0 = 0; k0 < K; k0 += TK) {
    if (k0) __syncthreads();
#pragma unroll
    for (int i = 0; i < 4; ++i) {
      int id = tid + i * 256;
      int r = id >> 3, oc = id & 7;
      int gr = row0 + r;
      bf16x8 sv;
      if (gr < M) sv = *(const bf16x8*)(A + (size_t)gr * lda + k0 + oc * 8);
      else sv = bf16x8{};
      int byte = (r * 128 + oc * 16) ^ ((r & 7) << 4);
      *(bf16x8*)(AsB + byte) = sv;
    }
#pragma unroll
    for (int i = 0; i < 2; ++i) {
      int id = tid + i * 256;
      int c = id >> 3, oc = id & 7;
      bf16x8 sv = *(const bf16x8*)(Wt + (size_t)(col0 + c) * K + k0 + oc * 8);
      int byte = (c * 128 + oc * 16) ^ ((c & 7) << 4);
      *(bf16x8*)(BtB + byte) = sv;
    }
    __syncthreads();
#pragma unroll
    for (int s = 0; s < 2; ++s) {
      bf16x8 af[4], bfr[2];
#pragma unroll
      for (int mi = 0; mi < 4; ++mi) {
        int r = wmB + mi * 16 + lr;
        int byte = (r * 128 + (s * 32 + lh * 8) * 2) ^ ((r & 7) << 4);
        af[mi] = *(const bf16x8*)(AsB + byte);
      }
#pragma unroll
      for (int ni = 0; ni < 2; ++ni) {
        int c = wnB + ni * 16 + lr;
        int byte = (c * 128 + (s * 32 + lh * 8) * 2) ^ ((c & 7) << 4);
        bfr[ni] = *(const bf16x8*)(BtB + byte);
      }
#pragma unroll
      for (int mi = 0; mi < 4; ++mi)
#pragma unroll
        for (int ni = 0; ni < 2; ++ni)
          acc[mi][ni] =
              __builtin_amdgcn_mfma_f32_16x16x32_bf16(af[mi], bfr[ni], acc[mi][ni], 0, 0, 0);
    }
  }
  // epilogue: C/D layout col = lane&15, row = (lane>>4)*4 + reg
  float cmax[2] = {-3.0e38f, -3.0e38f};  // raw-z colmax sentinel
#pragma unroll
  for (int mi = 0; mi < 4; ++mi) {
#pragma unroll
    for (int ni = 0; ni < 2; ++ni) {
#pragma unroll
      for (int r = 0; r < 4; ++r) {
        int gr = row0 + wmB + mi * 16 + lh * 4 + r;
        if (gr >= M) continue;
        int gc = col0 + wnB + ni * 16 + lr;
        size_t idx = (size_t)gr * Nout + gc;
        float v = acc[mi][ni][r];
        if (colAdd) v += colAdd[gc];
        if (doTanh) v = tanhf(v);
        if (colmaxOut) cmax[ni] = fmaxf(cmax[ni], v);
        if (Cf) Cf[idx] = v;
        if (Ch) Ch[idx] = (__bf16)v;
      }
    }
  }
  if (colmaxOut) {
#pragma unroll
    for (int ni = 0; ni < 2; ++ni) {
      float m = cmax[ni];
      m = fmaxf(m, __shfl_xor(m, 16));
      m = fmaxf(m, __shfl_xor(m, 32));
      if (lh == 0) {
        int gc = col0 + wnB + ni * 16 + lr;
        atomicMax(&colmaxOut[gc], enc_key(m));
      }
    }
  }
}

// ---------------- row load helper (f32 or bf16 input) ----------------
template <int VEC, typename IT>
static __device__ __forceinline__ void loadrow(const IT* p, float (&f)[VEC]) {
  if constexpr (sizeof(IT) == 4) {
    if constexpr (VEC == 4) {
      float4 h = *(const float4*)p;
      f[0] = h.x; f[1] = h.y; f[2] = h.z; f[3] = h.w;
    } else if constexpr (VEC == 2) {
      float2 h = *(const float2*)p;
      f[0] = h.x; f[1] = h.y;
    } else {
      f[0] = p[0];
    }
  } else {
    if constexpr (VEC == 4) {
      bf16x4 h = *(const bf16x4*)p;
      f[0] = (float)h[0]; f[1] = (float)h[1]; f[2] = (float)h[2]; f[3] = (float)h[3];
    } else if constexpr (VEC == 2) {
      bf16x2 h = *(const bf16x2*)p;
      f[0] = (float)h[0]; f[1] = (float)h[1];
    } else {
      f[0] = (float)p[0];
    }
  }
}

// ---------------- aggregation: out[d] = sum_{s in N(d)} H[s]*dis[s]*dis[d] + H[d]*dis[d]^2 ----------------
template <int F, bool EPI, typename IT, typename OT>
__global__ __launch_bounds__(256) void agg_kernel(
    const IT* __restrict__ H, const int* __restrict__ rowptr, const int* __restrict__ col,
    const float* __restrict__ dis, const float* __restrict__ bias, OT* __restrict__ out, int n) {
  constexpr int VEC = F / 64;
  int wid = (int)((blockIdx.x * blockDim.x + threadIdx.x) >> 6);
  int lane = threadIdx.x & 63;
  if (wid >= n) return;
  int node = __builtin_amdgcn_readfirstlane(wid);
  float dd = dis[node];
  float acc[VEC];
  {
    float h[VEC];
    loadrow<VEC, IT>(H + (size_t)node * F + lane * VEC, h);
#pragma unroll
    for (int i = 0; i < VEC; ++i) acc[i] = h[i] * dd * dd;
  }
  int beg = rowptr[node], end = rowptr[node + 1];
  for (int e = beg; e < end; ++e) {
    int s = col[e];
    float w = dis[s] * dd;
    float h[VEC];
    loadrow<VEC, IT>(H + (size_t)s * F + lane * VEC, h);
#pragma unroll
    for (int i = 0; i < VEC; ++i) acc[i] = fmaf(h[i], w, acc[i]);
  }
  OT* o = out + (size_t)node * F + lane * VEC;
#pragma unroll
  for (int i = 0; i < VEC; ++i) {
    float v = acc[i];
    if constexpr (EPI) v = tanhf(v + bias[lane * VEC + i]);
    o[i] = (OT)v;
  }
}

// crow[j] = sum_f tanh(maxz[f]) * W7top[f][j]  (tanh moved here by monotonicity)
__global__ __launch_bounds__(128) void crow_kernel(const unsigned* __restrict__ maxkey,
                                                   const float* __restrict__ W7top,
                                                   float* __restrict__ crow) {
  int j = threadIdx.x;  // 128
  float s = 0.f;
  for (int f = 0; f < 256; ++f) s = fmaf(tanhf(dec_key(maxkey[f])), W7top[f * 128 + j], s);
  crow[j] = s;
}

// ---------------- launch ----------------
extern "C" void kernel_launch(void* const* d_in, const int* in_sizes, int n_in,
                              void* d_out, int out_size, void* d_ws, size_t ws_size,
                              hipStream_t stream) {
  const float* x  = (const float*)d_in[0];
  const int* ei   = (const int*)d_in[1];
  const int* srcp = ei;
  const int* dstp = ei + EE;
  const float* W1 = (const float*)d_in[3];
  const float* b1 = (const float*)d_in[4];
  const float* W2 = (const float*)d_in[5];
  const float* b2 = (const float*)d_in[6];
  const float* W3 = (const float*)d_in[7];
  const float* b3 = (const float*)d_in[8];
  const float* W4 = (const float*)d_in[9];
  const float* b4 = (const float*)d_in[10];
  const float* W7 = (const float*)d_in[11];
  const float* b7 = (const float*)d_in[12];
  float* out = (float*)d_out;

  char* p = (char*)d_ws;
  auto alloc = [&](size_t bytes) -> void* {
    void* r = (void*)p;
    p += (bytes + 255) & ~(size_t)255;
    return r;
  };
  __bf16* T13  = (__bf16*)alloc((size_t)NN * 256 * 2);  // [t1|t3] bf16 (gather traffic halved)
  float*  H    = (float*)alloc((size_t)NN * 128 * 4);   // stage-5 f32 buffer
  __bf16* Hb13 = (__bf16*)alloc((size_t)NN * 256 * 2);  // agg([t1|t3]) bf16
  __bf16* Bb   = (__bf16*)alloc((size_t)NN * 256 * 2);  // i2 (bf16)
  float*  AX   = (float*)alloc((size_t)NN * 64 * 4);    // agg(x)
  __bf16* W2t  = (__bf16*)alloc((size_t)256 * 128 * 2);
  __bf16* W4t  = (__bf16*)alloc((size_t)256 * 128 * 2);
  __bf16* W7t  = (__bf16*)alloc((size_t)128 * 256 * 2);
  float*  Wcat = (float*)alloc((size_t)64 * 256 * 4);
  float*  bcat = (float*)alloc(256 * 4);
  float* dis = (float*)alloc((size_t)NN * 4);
  int* cnt = (int*)alloc((size_t)NN * 4);
  int* cursor = (int*)alloc((size_t)NN * 4);
  int* rowptr = (int*)alloc((size_t)(NN + 1) * 4);
  int* col = (int*)alloc((size_t)EE * 4);
  int* bsum = (int*)alloc(64 * 4);
  unsigned* maxkey = (unsigned*)alloc(256 * 4);
  float* crow = (float*)alloc(128 * 4);

  hipMemsetAsync(cnt, 0, (size_t)NN * 4, stream);
  hipMemsetAsync(cursor, 0, (size_t)NN * 4, stream);
  hipMemsetAsync(maxkey, 0, 256 * 4, stream);

  int eb = (EE + 255) / 256;
  int nb = (NN + 255) / 256;
  int nchunks = (NN + SCAN_CHUNK - 1) / SCAN_CHUNK;
  count_kernel<<<eb, 256, 0, stream>>>(dstp, cnt, EE);
  dis_kernel<<<nb, 256, 0, stream>>>(cnt, dis, NN);
  scan1_kernel<<<nchunks, 256, 0, stream>>>(cnt, rowptr, bsum, NN);
  scan2_kernel<<<1, 64, 0, stream>>>(bsum, nchunks);
  scan3_kernel<<<nb, 256, 0, stream>>>(rowptr, bsum, NN, EE);
  fill_kernel<<<eb, 256, 0, stream>>>(srcp, dstp, rowptr, cursor, col, EE);

  // weight prep — tiny one-shot work
  wcvt_kernel<<<(256 * 128 + 255) / 256, 256, 0, stream>>>(W2, W2t, 128, 256);
  wcvt_kernel<<<(256 * 128 + 255) / 256, 256, 0, stream>>>(W4, W4t, 128, 256);
  wcvt_kernel<<<(128 * 256 + 255) / 256, 256, 0, stream>>>(W7 + 256 * 128, W7t, 256, 128);
  wcat_kernel<<<(64 * 256 + 255) / 256, 256, 0, stream>>>(W1, W3, b1, b3, Wcat, bcat);

  dim3 gB(256);
  int mrows = (NN + BM - 1) / BM;   // 782 (f32 gemm)
  int mrowsT = (NN + TM - 1) / TM;  // 391 (mfma gemm)
  int aggB = (NN + 3) / 4;          // 1 wave/node

  // AX = agg(x)  [N,64]
  agg_kernel<64, false, float, float><<<aggB, gB, 0, stream>>>(x, rowptr, col, dis, nullptr, AX, NN);
  // merged stage 1+3: [t1|t3] = tanh(AX@[W1|W3] + [b1|b3]) -> T13  [N,256] bf16
  gemm_f32<__bf16><<<dim3(mrows, 4), gB, 0, stream>>>(AX, Wcat, T13, NN, 64, 256, bcat, 0, 1);
  // merged agg: Hb13 = agg(T13) (bf16 in, bf16 out)  [N,256]
  agg_kernel<256, false, __bf16, __bf16><<<aggB, gB, 0, stream>>>(T13, rowptr, col, dis, nullptr, Hb13, NN);
  // stage 2: colmax over raw z = Hb13[:,0:128]@W2 + b2 (tanh deferred; no stores)
  gemm_mfma<<<dim3(mrowsT, 4), gB, 0, stream>>>(Hb13, 256, W2t, nullptr, nullptr, NN, 128, 256, b2, 0, maxkey);
  // stage 4: i2 = tanh(Hb13[:,128:256]@W4 + b4) -> Bb (bf16)
  gemm_mfma<<<dim3(mrowsT, 4), gB, 0, stream>>>(Hb13 + 128, 256, W4t, nullptr, Bb, NN, 128, 256, b4, 1, nullptr);
  // stage 5: H = crow + i2@W7b (MFMA) ; H += x@W7c (f32) ; out = tanh(agg(H)+b7)
  crow_kernel<<<1, 128, 0, stream>>>(maxkey, W7, crow);
  gemm_mfma<<<dim3(mrowsT, 2), gB, 0, stream>>>(Bb, 256, W7t, H, nullptr, NN, 256, 128, crow, 0, nullptr);
  gemm_f32<float><<<dim3(mrows, 2), gB, 0, stream>>>(x, W7 + 512 * 128, H, NN, 64, 128, nullptr, 1, 0);
  agg_kernel<128, true, float, float><<<aggB, gB, 0, stream>>>(H, rowptr, col, dis, b7, out, NN);
}

// Round 15
// 424.233 us; speedup vs baseline: 1.1654x; 1.0782x over previous
//
#include <hip/hip_runtime.h>
#include <hip/hip_bf16.h>
#include <cstdint>
#include <cstddef>

#define NN 50000
#define EE 400000

typedef __attribute__((ext_vector_type(8))) __bf16 bf16x8;
typedef __attribute__((ext_vector_type(4))) __bf16 bf16x4;
typedef __attribute__((ext_vector_type(2))) __bf16 bf16x2;
typedef __attribute__((ext_vector_type(4))) float f32x4;

// ---------------- CSR build ----------------
__global__ void count_kernel(const int* __restrict__ dst, int* __restrict__ cnt, int e) {
  int i = blockIdx.x * blockDim.x + threadIdx.x;
  if (i < e) atomicAdd(&cnt[dst[i]], 1);
}

__global__ void dis_kernel(const int* __restrict__ cnt, float* __restrict__ dis, int n) {
  int i = blockIdx.x * blockDim.x + threadIdx.x;
  if (i < n) dis[i] = rsqrtf((float)cnt[i] + 1.0f);
}

#define SCAN_CHUNK 1024
__global__ __launch_bounds__(256) void scan1_kernel(const int* __restrict__ cnt,
                                                    int* __restrict__ rowptr,
                                                    int* __restrict__ bsum, int n) {
  int b = blockIdx.x;
  int base = b * SCAN_CHUNK;
  int t = threadIdx.x;
  int v[4];
  int s = 0;
#pragma unroll
  for (int i = 0; i < 4; ++i) {
    int idx = base + t * 4 + i;
    v[i] = (idx < n) ? cnt[idx] : 0;
    s += v[i];
  }
  int lane = t & 63, w = t >> 6;
  int inc = s;
#pragma unroll
  for (int off = 1; off < 64; off <<= 1) {
    int o = __shfl_up(inc, off, 64);
    if (lane >= off) inc += o;
  }
  __shared__ int wsum[4];
  if (lane == 63) wsum[w] = inc;
  __syncthreads();
  int woff = 0;
  for (int i = 0; i < w; ++i) woff += wsum[i];
  int run = woff + inc - s;
#pragma unroll
  for (int i = 0; i < 4; ++i) {
    int idx = base + t * 4 + i;
    if (idx < n) rowptr[idx] = run;
    run += v[i];
  }
  if (t == 255) bsum[b] = woff + inc;
}

__global__ void scan2_kernel(int* __restrict__ bsum, int nb) {
  int t = threadIdx.x;
  int v = (t < nb) ? bsum[t] : 0;
  int s = v;
#pragma unroll
  for (int off = 1; off < 64; off <<= 1) {
    int o = __shfl_up(s, off, 64);
    if (t >= off) s += o;
  }
  if (t < nb) bsum[t] = s - v;
}

__global__ __launch_bounds__(256) void scan3_kernel(int* __restrict__ rowptr,
                                                    const int* __restrict__ bsum, int n, int total) {
  int i = blockIdx.x * blockDim.x + threadIdx.x;
  if (i < n) rowptr[i] += bsum[i >> 10];
  if (i == 0) rowptr[n] = total;
}

__global__ void fill_kernel(const int* __restrict__ src, const int* __restrict__ dst,
                            const int* __restrict__ rowptr, int* __restrict__ cursor,
                            int* __restrict__ col, int e) {
  int i = blockIdx.x * blockDim.x + threadIdx.x;
  if (i < e) {
    int d = dst[i];
    int p = atomicAdd(&cursor[d], 1);
    col[rowptr[d] + p] = src[i];
  }
}

// ---------------- weight cvt+transpose: Wt[n][k] = bf16(W[k][n]) ----------------
__global__ __launch_bounds__(256) void wcvt_kernel(const float* __restrict__ W,
                                                   __bf16* __restrict__ Wt, int K, int Nout) {
  int idx = blockIdx.x * blockDim.x + threadIdx.x;
  if (idx < K * Nout) {
    int n = idx / K, k = idx - n * K;
    Wt[idx] = (__bf16)W[(size_t)k * Nout + n];
  }
}

// ---------------- concat [W1|W3] -> Wcat[64][256] f32, bcat[256] ----------------
__global__ __launch_bounds__(256) void wcat_kernel(const float* __restrict__ W1,
                                                   const float* __restrict__ W3,
                                                   const float* __restrict__ b1,
                                                   const float* __restrict__ b3,
                                                   float* __restrict__ Wcat,
                                                   float* __restrict__ bcat) {
  int idx = blockIdx.x * blockDim.x + threadIdx.x;
  if (idx < 64 * 256) {
    int k = idx >> 8, j = idx & 255;
    Wcat[idx] = (j < 128) ? W1[k * 128 + j] : W3[k * 128 + (j - 128)];
  }
  if (idx < 256) bcat[idx] = (idx < 128) ? b1[idx] : b3[idx - 128];
}

// ---------------- f32 GEMM: C = A@W, fused epilogue; output type templated ----------------
#define BM 64
#define BN 64
#define BK 16

template <typename OT>
__global__ __launch_bounds__(256) void gemm_f32(
    const float* __restrict__ A, const float* __restrict__ W, OT* __restrict__ C,
    int M, int K, int Nout, const float* __restrict__ colAdd, int accumulate, int doTanh) {
  __shared__ float As[BK][BM + 4];
  __shared__ float Ws[BK][BN];
  int tid = threadIdx.x;
  int row0 = blockIdx.x * BM;
  int col0 = blockIdx.y * BN;
  int tx = tid & 15;
  int ty = tid >> 4;
  float acc[4][4] = {};
  for (int k0 = 0; k0 < K; k0 += BK) {
#pragma unroll
    for (int i = 0; i < 4; ++i) {
      int idx = tid + i * 256;
      int r = idx >> 4, c = idx & 15;
      int gr = row0 + r;
      float v = (gr < M) ? A[(size_t)gr * K + k0 + c] : 0.f;
      As[c][r] = v;
    }
#pragma unroll
    for (int i = 0; i < 4; ++i) {
      int idx = tid + i * 256;
      int r = idx >> 6, c = idx & 63;
      Ws[r][c] = W[(size_t)(k0 + r) * Nout + col0 + c];
    }
    __syncthreads();
#pragma unroll
    for (int kk = 0; kk < BK; ++kk) {
      float4 av = *(const float4*)&As[kk][ty * 4];
      float4 wv = *(const float4*)&Ws[kk][tx * 4];
      float a[4] = {av.x, av.y, av.z, av.w};
      float w[4] = {wv.x, wv.y, wv.z, wv.w};
#pragma unroll
      for (int i = 0; i < 4; ++i)
#pragma unroll
        for (int j = 0; j < 4; ++j) acc[i][j] = fmaf(a[i], w[j], acc[i][j]);
    }
    __syncthreads();
  }
#pragma unroll
  for (int i = 0; i < 4; ++i) {
    int gr = row0 + ty * 4 + i;
    if (gr >= M) continue;
#pragma unroll
    for (int j = 0; j < 4; ++j) {
      int gc = col0 + tx * 4 + j;
      size_t idx = (size_t)gr * Nout + gc;
      float v = acc[i][j];
      if (colAdd) v += colAdd[gc];
      if (accumulate) v += (float)C[idx];
      if (doTanh) v = tanhf(v);
      C[idx] = (OT)v;
    }
  }
}

// ---------------- bf16 MFMA GEMM (LDS-staged, 64x64 tile, lda) ----------------
// A[M,*](bf16, row stride lda) @ Wt[Nout,K](bf16 pre-transposed). 64x64 tile,
// BK=64, 4 waves each 32x32, XOR-swizzled LDS, staging = pure 16B copies.
// colmaxPart (stage-2): per-block column maxima of raw z stored (no atomics) to
// partialT[col][blockIdx.x*2 + mhalf]; reduced by colreduce_kernel.
#define TM 64
#define TN 64
#define TK 64
#define CSLOTS 1568  // 2*782 padded

__global__ __launch_bounds__(256) void gemm_mfma(
    const __bf16* __restrict__ A, int lda, const __bf16* __restrict__ Wt,
    float* __restrict__ Cf, __bf16* __restrict__ Ch,
    int M, int K, int Nout, const float* __restrict__ colAdd, int doTanh,
    float* __restrict__ colmaxPart) {
  __shared__ char lds[(TM * TK + TN * TK) * 2];  // As bf16[64][64], Bt bf16[64][64]
  char* AsB = lds;
  char* BtB = lds + TM * TK * 2;
  int tid = threadIdx.x;
  int row0 = blockIdx.x * TM;
  int col0 = blockIdx.y * TN;
  int w = tid >> 6, l = tid & 63;
  int lr = l & 15, lh = l >> 4;
  int wmB = (w >> 1) * 32;  // wave row base within tile
  int wnB = (w & 1) * 32;   // wave col base within tile
  f32x4 acc[2][2] = {};
  for (int k0 = 0; k0 < K; k0 += TK) {
    if (k0) __syncthreads();
    // stage A: 2 octets (16B) per thread, swz byte ^= (row&7)<<4
#pragma unroll
    for (int i = 0; i < 2; ++i) {
      int id = tid + i * 256;
      int r = id >> 3, oc = id & 7;
      int gr = row0 + r;
      bf16x8 sv;
      if (gr < M) sv = *(const bf16x8*)(A + (size_t)gr * lda + k0 + oc * 8);
      else sv = bf16x8{};
      int byte = (r * 128 + oc * 16) ^ ((r & 7) << 4);
      *(bf16x8*)(AsB + byte) = sv;
    }
    // stage Bt: 2 octets per thread from pre-transposed bf16 weights
#pragma unroll
    for (int i = 0; i < 2; ++i) {
      int id = tid + i * 256;
      int c = id >> 3, oc = id & 7;
      bf16x8 sv = *(const bf16x8*)(Wt + (size_t)(col0 + c) * K + k0 + oc * 8);
      int byte = (c * 128 + oc * 16) ^ ((c & 7) << 4);
      *(bf16x8*)(BtB + byte) = sv;
    }
    __syncthreads();
    // 2 MFMA k-steps of 32
#pragma unroll
    for (int s = 0; s < 2; ++s) {
      bf16x8 af[2], bfr[2];
#pragma unroll
      for (int mi = 0; mi < 2; ++mi) {
        int r = wmB + mi * 16 + lr;
        int byte = (r * 128 + (s * 32 + lh * 8) * 2) ^ ((r & 7) << 4);
        af[mi] = *(const bf16x8*)(AsB + byte);
      }
#pragma unroll
      for (int ni = 0; ni < 2; ++ni) {
        int c = wnB + ni * 16 + lr;
        int byte = (c * 128 + (s * 32 + lh * 8) * 2) ^ ((c & 7) << 4);
        bfr[ni] = *(const bf16x8*)(BtB + byte);
      }
#pragma unroll
      for (int mi = 0; mi < 2; ++mi)
#pragma unroll
        for (int ni = 0; ni < 2; ++ni)
          acc[mi][ni] =
              __builtin_amdgcn_mfma_f32_16x16x32_bf16(af[mi], bfr[ni], acc[mi][ni], 0, 0, 0);
    }
  }
  // epilogue: C/D layout col = lane&15, row = (lane>>4)*4 + reg
  float cmax[2] = {-3.0e38f, -3.0e38f};
#pragma unroll
  for (int mi = 0; mi < 2; ++mi) {
#pragma unroll
    for (int ni = 0; ni < 2; ++ni) {
#pragma unroll
      for (int r = 0; r < 4; ++r) {
        int gr = row0 + wmB + mi * 16 + lh * 4 + r;
        if (gr >= M) continue;
        int gc = col0 + wnB + ni * 16 + lr;
        size_t idx = (size_t)gr * Nout + gc;
        float v = acc[mi][ni][r];
        if (colAdd) v += colAdd[gc];
        if (doTanh) v = tanhf(v);
        if (colmaxPart) cmax[ni] = fmaxf(cmax[ni], v);
        if (Cf) Cf[idx] = v;
        if (Ch) Ch[idx] = (__bf16)v;
      }
    }
  }
  if (colmaxPart) {
    // reduce over the wave's 4 lane-groups, then plain store (no atomics):
    // slot = blockIdx.x*2 + (w>>1); each (col, slot) written by exactly one lane.
#pragma unroll
    for (int ni = 0; ni < 2; ++ni) {
      float m = cmax[ni];
      m = fmaxf(m, __shfl_xor(m, 16));
      m = fmaxf(m, __shfl_xor(m, 32));
      if (lh == 0) {
        int gc = col0 + wnB + ni * 16 + lr;
        colmaxPart[(size_t)gc * CSLOTS + blockIdx.x * 2 + (w >> 1)] = m;
      }
    }
  }
}

// reduce partialT[256][CSLOTS] -> maxz[256]
__global__ __launch_bounds__(64) void colreduce_kernel(const float* __restrict__ part,
                                                       float* __restrict__ maxz, int nslots) {
  int c = blockIdx.x;
  int t = threadIdx.x;
  float m = -3.0e38f;
  for (int i = t; i < nslots; i += 64) m = fmaxf(m, part[(size_t)c * CSLOTS + i]);
#pragma unroll
  for (int off = 32; off >= 1; off >>= 1) m = fmaxf(m, __shfl_xor(m, off));
  if (t == 0) maxz[c] = m;
}

// ---------------- row load helper (f32 or bf16 input) ----------------
template <int VEC, typename IT>
static __device__ __forceinline__ void loadrow(const IT* p, float (&f)[VEC]) {
  if constexpr (sizeof(IT) == 4) {
    if constexpr (VEC == 4) {
      float4 h = *(const float4*)p;
      f[0] = h.x; f[1] = h.y; f[2] = h.z; f[3] = h.w;
    } else if constexpr (VEC == 2) {
      float2 h = *(const float2*)p;
      f[0] = h.x; f[1] = h.y;
    } else {
      f[0] = p[0];
    }
  } else {
    if constexpr (VEC == 4) {
      bf16x4 h = *(const bf16x4*)p;
      f[0] = (float)h[0]; f[1] = (float)h[1]; f[2] = (float)h[2]; f[3] = (float)h[3];
    } else if constexpr (VEC == 2) {
      bf16x2 h = *(const bf16x2*)p;
      f[0] = (float)h[0]; f[1] = (float)h[1];
    } else {
      f[0] = (float)p[0];
    }
  }
}

// ---------------- aggregation: out[d] = sum_{s in N(d)} H[s]*dis[s]*dis[d] + H[d]*dis[d]^2 ----------------
template <int F, bool EPI, typename IT, typename OT>
__global__ __launch_bounds__(256) void agg_kernel(
    const IT* __restrict__ H, const int* __restrict__ rowptr, const int* __restrict__ col,
    const float* __restrict__ dis, const float* __restrict__ bias, OT* __restrict__ out, int n) {
  constexpr int VEC = F / 64;
  int wid = (int)((blockIdx.x * blockDim.x + threadIdx.x) >> 6);
  int lane = threadIdx.x & 63;
  if (wid >= n) return;
  int node = __builtin_amdgcn_readfirstlane(wid);
  float dd = dis[node];
  float acc[VEC];
  {
    float h[VEC];
    loadrow<VEC, IT>(H + (size_t)node * F + lane * VEC, h);
#pragma unroll
    for (int i = 0; i < VEC; ++i) acc[i] = h[i] * dd * dd;
  }
  int beg = rowptr[node], end = rowptr[node + 1];
  for (int e = beg; e < end; ++e) {
    int s = col[e];
    float w = dis[s] * dd;
    float h[VEC];
    loadrow<VEC, IT>(H + (size_t)s * F + lane * VEC, h);
#pragma unroll
    for (int i = 0; i < VEC; ++i) acc[i] = fmaf(h[i], w, acc[i]);
  }
  OT* o = out + (size_t)node * F + lane * VEC;
#pragma unroll
  for (int i = 0; i < VEC; ++i) {
    float v = acc[i];
    if constexpr (EPI) v = tanhf(v + bias[lane * VEC + i]);
    o[i] = (OT)v;
  }
}

// crow[j] = sum_f tanh(maxz[f]) * W7top[f][j]  (tanh here by monotonicity)
__global__ __launch_bounds__(128) void crow_kernel(const float* __restrict__ maxz,
                                                   const float* __restrict__ W7top,
                                                   float* __restrict__ crow) {
  int j = threadIdx.x;  // 128
  float s = 0.f;
  for (int f = 0; f < 256; ++f) s = fmaf(tanhf(maxz[f]), W7top[f * 128 + j], s);
  crow[j] = s;
}

// ---------------- launch ----------------
extern "C" void kernel_launch(void* const* d_in, const int* in_sizes, int n_in,
                              void* d_out, int out_size, void* d_ws, size_t ws_size,
                              hipStream_t stream) {
  const float* x  = (const float*)d_in[0];
  const int* ei   = (const int*)d_in[1];
  const int* srcp = ei;
  const int* dstp = ei + EE;
  const float* W1 = (const float*)d_in[3];
  const float* b1 = (const float*)d_in[4];
  const float* W2 = (const float*)d_in[5];
  const float* b2 = (const float*)d_in[6];
  const float* W3 = (const float*)d_in[7];
  const float* b3 = (const float*)d_in[8];
  const float* W4 = (const float*)d_in[9];
  const float* b4 = (const float*)d_in[10];
  const float* W7 = (const float*)d_in[11];
  const float* b7 = (const float*)d_in[12];
  float* out = (float*)d_out;

  char* p = (char*)d_ws;
  auto alloc = [&](size_t bytes) -> void* {
    void* r = (void*)p;
    p += (bytes + 255) & ~(size_t)255;
    return r;
  };
  __bf16* T13  = (__bf16*)alloc((size_t)NN * 256 * 2);  // [t1|t3] bf16
  float*  H    = (float*)alloc((size_t)NN * 128 * 4);   // stage-5 f32 buffer
  __bf16* Hb13 = (__bf16*)alloc((size_t)NN * 256 * 2);  // agg([t1|t3]) bf16
  __bf16* Bb   = (__bf16*)alloc((size_t)NN * 256 * 2);  // i2 (bf16)
  float*  AX   = (float*)alloc((size_t)NN * 64 * 4);    // agg(x)
  __bf16* W2t  = (__bf16*)alloc((size_t)256 * 128 * 2);
  __bf16* W4t  = (__bf16*)alloc((size_t)256 * 128 * 2);
  __bf16* W7t  = (__bf16*)alloc((size_t)128 * 256 * 2);
  float*  Wcat = (float*)alloc((size_t)64 * 256 * 4);
  float*  bcat = (float*)alloc(256 * 4);
  float*  cpart = (float*)alloc((size_t)256 * CSLOTS * 4);  // colmax partials
  float*  maxz  = (float*)alloc(256 * 4);
  float* dis = (float*)alloc((size_t)NN * 4);
  int* cnt = (int*)alloc((size_t)NN * 4);
  int* cursor = (int*)alloc((size_t)NN * 4);
  int* rowptr = (int*)alloc((size_t)(NN + 1) * 4);
  int* col = (int*)alloc((size_t)EE * 4);
  int* bsum = (int*)alloc(64 * 4);
  float* crow = (float*)alloc(128 * 4);

  hipMemsetAsync(cnt, 0, (size_t)NN * 4, stream);
  hipMemsetAsync(cursor, 0, (size_t)NN * 4, stream);

  int eb = (EE + 255) / 256;
  int nb = (NN + 255) / 256;
  int nchunks = (NN + SCAN_CHUNK - 1) / SCAN_CHUNK;
  count_kernel<<<eb, 256, 0, stream>>>(dstp, cnt, EE);
  dis_kernel<<<nb, 256, 0, stream>>>(cnt, dis, NN);
  scan1_kernel<<<nchunks, 256, 0, stream>>>(cnt, rowptr, bsum, NN);
  scan2_kernel<<<1, 64, 0, stream>>>(bsum, nchunks);
  scan3_kernel<<<nb, 256, 0, stream>>>(rowptr, bsum, NN, EE);
  fill_kernel<<<eb, 256, 0, stream>>>(srcp, dstp, rowptr, cursor, col, EE);

  // weight prep — tiny one-shot work
  wcvt_kernel<<<(256 * 128 + 255) / 256, 256, 0, stream>>>(W2, W2t, 128, 256);
  wcvt_kernel<<<(256 * 128 + 255) / 256, 256, 0, stream>>>(W4, W4t, 128, 256);
  wcvt_kernel<<<(128 * 256 + 255) / 256, 256, 0, stream>>>(W7 + 256 * 128, W7t, 256, 128);
  wcat_kernel<<<(64 * 256 + 255) / 256, 256, 0, stream>>>(W1, W3, b1, b3, Wcat, bcat);

  dim3 gB(256);
  int mrows = (NN + BM - 1) / BM;   // 782 (f32 gemm)
  int mrowsT = (NN + TM - 1) / TM;  // 782 (mfma gemm, TM=64)
  int aggB = (NN + 3) / 4;          // 1 wave/node

  // AX = agg(x)  [N,64]
  agg_kernel<64, false, float, float><<<aggB, gB, 0, stream>>>(x, rowptr, col, dis, nullptr, AX, NN);
  // merged stage 1+3: [t1|t3] = tanh(AX@[W1|W3] + [b1|b3]) -> T13  [N,256] bf16
  gemm_f32<__bf16><<<dim3(mrows, 4), gB, 0, stream>>>(AX, Wcat, T13, NN, 64, 256, bcat, 0, 1);
  // merged agg: Hb13 = agg(T13) (bf16 in/out)  [N,256]
  agg_kernel<256, false, __bf16, __bf16><<<aggB, gB, 0, stream>>>(T13, rowptr, col, dis, nullptr, Hb13, NN);
  // stage 2: per-block colmax partials of raw z = Hb13[:,0:128]@W2 + b2 (no stores, no atomics)
  gemm_mfma<<<dim3(mrowsT, 4), gB, 0, stream>>>(Hb13, 256, W2t, nullptr, nullptr, NN, 128, 256, b2, 0, cpart);
  colreduce_kernel<<<256, 64, 0, stream>>>(cpart, maxz, mrowsT * 2);
  // stage 4: i2 = tanh(Hb13[:,128:256]@W4 + b4) -> Bb (bf16)
  gemm_mfma<<<dim3(mrowsT, 4), gB, 0, stream>>>(Hb13 + 128, 256, W4t, nullptr, Bb, NN, 128, 256, b4, 1, nullptr);
  // stage 5: H = crow + i2@W7b (MFMA) ; H += x@W7c (f32) ; out = tanh(agg(H)+b7)
  crow_kernel<<<1, 128, 0, stream>>>(maxz, W7, crow);
  gemm_mfma<<<dim3(mrowsT, 2), gB, 0, stream>>>(Bb, 256, W7t, H, nullptr, NN, 256, 128, crow, 0, nullptr);
  gemm_f32<float><<<dim3(mrows, 2), gB, 0, stream>>>(x, W7 + 512 * 128, H, NN, 64, 128, nullptr, 1, 0);
  agg_kernel<128, true, float, float><<<aggB, gB, 0, stream>>>(H, rowptr, col, dis, b7, out, NN);
}